// Round 17
// baseline (342.078 us; speedup 1.0000x reference)
//
#include <hip/hip_runtime.h>
#include <hip/hip_bf16.h>

typedef __attribute__((ext_vector_type(8))) short short8_t;
typedef __attribute__((ext_vector_type(4))) float f32x4;

__device__ __forceinline__ short f2bf(float x){
  union { float f; unsigned u; } v; v.f = x;
  unsigned r = v.u + 0x7fffu + ((v.u >> 16) & 1u);
  return (short)(r >> 16);
}
__device__ __forceinline__ float bf2f(unsigned short u){
  union { unsigned u; float f; } v; v.u = ((unsigned)u) << 16; return v.f;
}
// non-volatile pure value op: compiler schedules freely
__device__ __forceinline__ unsigned cvtpk(float lo, float hi){
  unsigned r; asm("v_cvt_pk_bf16_f32 %0, %1, %2" : "=v"(r) : "v"(lo), "v"(hi)); return r;
}
// async global->LDS, 16B/lane, LDS dest = uniform base + lane*16 (linear)
__device__ __forceinline__ void gll16(const float* g, void* l){
  __builtin_amdgcn_global_load_lds((const __attribute__((address_space(1))) char*)g,
                                   (__attribute__((address_space(3))) char*)l, 16, 0, 0);
}

// Both W -> bf16 fragment layouts in one launch.
__global__ __launch_bounds__(256) void k_wconv2(const float* __restrict__ W1, short* __restrict__ Wb1,
                                                const float* __restrict__ W2, short* __restrict__ Wb2){
  int tid = blockIdx.x*256 + threadIdx.x;
  const float* W; short* Wb; int t;
  if (tid < 64*2048){ W = W1; Wb = Wb1; t = tid; }
  else if (tid < 64*2048 + 2*2048){ W = W2; Wb = Wb2; t = tid - 64*2048; }
  else return;
  int e  = t & 7;
  int l  = (t >> 3) & 63;
  int nt = (t >> 9) & 3;
  int kt = t >> 11;
  int k  = kt*32 + (l >> 4)*8 + e;
  int col = nt*16 + (l & 15);
  Wb[t] = f2bf(W[(size_t)k*64 + col]);
}

// GEMM1 — R12-exact staging (best measured: total 319.6us): per-row gll16 x16 into
// 1040B-pitch LDS, vmcnt(0) drain per 256-col ko-step, 66.5KB -> 2 blocks/CU.
// cvt_pk on consume (zero staging VALU). Unscaled bf16 out + sharded hist tail.
__global__ __launch_bounds__(256) void k_gemm1_hist(const float* __restrict__ A, const short* __restrict__ Wb,
                                                    unsigned short* __restrict__ h1, int M,
                                                    const int* __restrict__ ei, int* __restrict__ cnt16,
                                                    int* __restrict__ rank, int E, int N){
  __shared__ char lds[4*16*1040];   // 66560 B -> 2 blocks/CU
  int b = blockIdx.x, tid = threadIdx.x;
  int wid = tid >> 6, lane = tid & 63;
  int row0 = b*64 + wid*16;
  int rfrag = lane & 15, grp = lane >> 4;
  char* wls = lds + wid*16*1040;    // wave-private region: no barriers
  const short8_t* wb = (const short8_t*)Wb + lane;
  f32x4 acc0 = {0.f,0.f,0.f,0.f}, acc1 = acc0, acc2 = acc0, acc3 = acc0;

  int rowc[16];
  #pragma unroll
  for (int r = 0; r < 16; ++r){
    int rc = row0 + r; rowc[r] = (rc < M) ? rc : (M - 1);
  }

  for (int ko = 0; ko < 8; ++ko){
    #pragma unroll
    for (int r = 0; r < 16; ++r)
      gll16(A + (size_t)rowc[r]*2048 + ko*256 + lane*4, wls + r*1040);
    asm volatile("s_waitcnt vmcnt(0)" ::: "memory");
    __builtin_amdgcn_sched_barrier(0);
    #pragma unroll
    for (int kt = 0; kt < 8; ++kt){
      const float* fp = (const float*)(wls + rfrag*1040 + (kt*32 + grp*8)*4);
      float4 a0 = *(const float4*)fp;
      float4 a1 = *(const float4*)(fp + 4);
      union { unsigned u[4]; short8_t s; } af;
      af.u[0] = cvtpk(a0.x, a0.y);
      af.u[1] = cvtpk(a0.z, a0.w);
      af.u[2] = cvtpk(a1.x, a1.y);
      af.u[3] = cvtpk(a1.z, a1.w);
      int ktg = ko*8 + kt;
      short8_t b0 = wb[(ktg*4+0)*64];
      short8_t b1 = wb[(ktg*4+1)*64];
      short8_t b2 = wb[(ktg*4+2)*64];
      short8_t b3 = wb[(ktg*4+3)*64];
      acc0 = __builtin_amdgcn_mfma_f32_16x16x32_bf16(af.s, b0, acc0, 0,0,0);
      acc1 = __builtin_amdgcn_mfma_f32_16x16x32_bf16(af.s, b1, acc1, 0,0,0);
      acc2 = __builtin_amdgcn_mfma_f32_16x16x32_bf16(af.s, b2, acc2, 0,0,0);
      acc3 = __builtin_amdgcn_mfma_f32_16x16x32_bf16(af.s, b3, acc3, 0,0,0);
    }
  }

  // C/D: col = lane&15, row = (lane>>4)*4 + reg ; unscaled bf16, guarded
  int orow = row0 + grp*4;
  unsigned short* op = h1 + (size_t)orow*64 + rfrag;
  #pragma unroll
  for (int reg = 0; reg < 4; ++reg){
    if (orow + reg < M){
      op[reg*64 +  0] = (unsigned short)f2bf(acc0[reg]);
      op[reg*64 + 16] = (unsigned short)f2bf(acc1[reg]);
      op[reg*64 + 32] = (unsigned short)f2bf(acc2[reg]);
      op[reg*64 + 48] = (unsigned short)f2bf(acc3[reg]);
    }
  }

  // ---- tail: sharded histogram slice (2048 edges/block, shard = b&15) ----
  int lo = b << 11, hi = lo + 2048; if (hi > E) hi = E;
  int* cs = cnt16 + (size_t)(b & 15)*N;
  for (int i = lo + tid; i < hi; i += 256)
    rank[i] = atomicAdd(&cs[ei[E + i]], 1);
}

// ---- parallel scan over sharded counts ----
__global__ __launch_bounds__(256) void k_part(const int* __restrict__ cnt16, int* __restrict__ partial, int N){
  int b = blockIdx.x, t = threadIdx.x;
  int chunk = (N + 255) >> 8;
  int lo = b*chunk, hi = lo + chunk; if (hi > N) hi = N;
  int s = 0;
  for (int i = lo + t; i < hi; i += 256){
    #pragma unroll
    for (int sh = 0; sh < 16; ++sh) s += cnt16[(size_t)sh*N + i];
  }
  __shared__ int sm[256];
  sm[t] = s; __syncthreads();
  for (int d = 128; d; d >>= 1){ if (t < d) sm[t] += sm[t+d]; __syncthreads(); }
  if (t == 0) partial[b] = sm[0];
}

__global__ __launch_bounds__(256) void k_scan2(const int* __restrict__ cnt16, const int* __restrict__ partial,
                                               int* __restrict__ off, int* __restrict__ sbase,
                                               float* __restrict__ dinv, int N){
  int b = blockIdx.x, t = threadIdx.x;
  __shared__ int ps[256];
  ps[t] = partial[t]; __syncthreads();
  for (int d = 1; d < 256; d <<= 1){
    int v = (t >= d) ? ps[t-d] : 0; __syncthreads(); ps[t] += v; __syncthreads();
  }
  int base  = b ? ps[b-1] : 0;
  int total = ps[255];
  int chunk = (N + 255) >> 8;
  int lo = b*chunk, hi = lo + chunk; if (hi > N) hi = N;
  __shared__ int vs[256];
  int run = base;
  for (int j0 = lo; j0 < hi; j0 += 256){
    int i = j0 + t;
    int cs[16]; int c = 0;
    if (i < hi){
      #pragma unroll
      for (int sh = 0; sh < 16; ++sh){ cs[sh] = cnt16[(size_t)sh*N + i]; c += cs[sh]; }
    }
    vs[t] = (i < hi) ? c : 0; __syncthreads();
    for (int d = 1; d < 256; d <<= 1){
      int v = (t >= d) ? vs[t-d] : 0; __syncthreads(); vs[t] += v; __syncthreads();
    }
    if (i < hi){
      int excl = run + vs[t] - c;
      off[i] = excl;
      dinv[i] = rsqrtf((float)(c + 1));
      int runs = excl;
      #pragma unroll
      for (int sh = 0; sh < 16; ++sh){ sbase[(size_t)sh*N + i] = runs; runs += cs[sh]; }
    }
    run += vs[255];
    __syncthreads();
  }
  if (b == 255 && t == 0) off[N] = total;
}

// Atomic-free scatter: shard = (i>>11)&15 (matches 2048-edge hist slices).
__global__ __launch_bounds__(256) void k_scatter(const int* __restrict__ ei, const int* __restrict__ sbase,
                                                 const int* __restrict__ rank, int* __restrict__ ebuf,
                                                 int E, int N){
  int i = blockIdx.x*256 + threadIdx.x;
  if (i < E){
    int s = ei[i], d = ei[E + i];
    int sh = (i >> 11) & 15;
    ebuf[sbase[(size_t)sh*N + d] + rank[i]] = s;
  }
}

// GEMM2 (K=64): bf16 A, unscaled bf16 out.
template<int KTILES>
__global__ __launch_bounds__(256) void k_gemm_sm(const unsigned short* __restrict__ Ah,
                                                 const short* __restrict__ Wb,
                                                 unsigned short* __restrict__ out, int M, int lda){
  int wid = threadIdx.x >> 6, lane = threadIdx.x & 63;
  int row0 = (blockIdx.x*4 + wid)*16;
  if (row0 >= M) return;
  int r = lane & 15, g = lane >> 4;
  const short8_t* wb = (const short8_t*)Wb + lane;
  f32x4 acc0 = {0.f,0.f,0.f,0.f}, acc1 = acc0, acc2 = acc0, acc3 = acc0;
  #pragma unroll
  for (int kt = 0; kt < KTILES; ++kt){
    short8_t af = *(const short8_t*)(Ah + (size_t)(row0 + r)*lda + kt*32 + g*8);
    short8_t b0 = wb[(kt*4+0)*64];
    short8_t b1 = wb[(kt*4+1)*64];
    short8_t b2 = wb[(kt*4+2)*64];
    short8_t b3 = wb[(kt*4+3)*64];
    acc0 = __builtin_amdgcn_mfma_f32_16x16x32_bf16(af, b0, acc0, 0,0,0);
    acc1 = __builtin_amdgcn_mfma_f32_16x16x32_bf16(af, b1, acc1, 0,0,0);
    acc2 = __builtin_amdgcn_mfma_f32_16x16x32_bf16(af, b2, acc2, 0,0,0);
    acc3 = __builtin_amdgcn_mfma_f32_16x16x32_bf16(af, b3, acc3, 0,0,0);
  }
  int orow = row0 + g*4;
  unsigned short* op = out + (size_t)orow*64 + r;
  #pragma unroll
  for (int reg = 0; reg < 4; ++reg){
    if (orow + reg < M){
      op[reg*64 +  0] = (unsigned short)f2bf(acc0[reg]);
      op[reg*64 + 16] = (unsigned short)f2bf(acc1[reg]);
      op[reg*64 + 32] = (unsigned short)f2bf(acc2[reg]);
      op[reg*64 + 48] = (unsigned short)f2bf(acc3[reg]);
    }
  }
}

// Gather-aggregate on unscaled h, 16-deep gather pipeline (static unrolled arrays).
template<bool FUSE>
__global__ __launch_bounds__(256) void k_agg(const unsigned short* __restrict__ hin, const int* __restrict__ off,
                                             const int* __restrict__ ebuf, const float* __restrict__ dinv,
                                             const float* __restrict__ bias, void* __restrict__ outp, int N){
  int lane = threadIdx.x & 63, wid = threadIdx.x >> 6;
  float b = bias[lane];
  float fsum = 0.f;
  int stride = gridDim.x*4;
  for (int i = blockIdx.x*4 + wid; i < N; i += stride){
    float di = dinv[i];
    float acc = di*bf2f(hin[(size_t)i*64 + lane]);
    int j  = off[i];
    int j1 = off[i+1];
    for (; j + 16 <= j1; j += 16){
      int s[16]; float wgt[16]; float hv[16];
      #pragma unroll
      for (int q = 0; q < 16; ++q) s[q] = ebuf[j + q];
      #pragma unroll
      for (int q = 0; q < 16; ++q) wgt[q] = dinv[s[q]];
      #pragma unroll
      for (int q = 0; q < 16; ++q) hv[q] = bf2f(hin[(size_t)s[q]*64 + lane]);
      #pragma unroll
      for (int q = 0; q < 16; ++q) acc += wgt[q]*hv[q];
    }
    for (; j + 4 <= j1; j += 4){
      int s0 = ebuf[j], s1 = ebuf[j+1], s2 = ebuf[j+2], s3 = ebuf[j+3];
      float w0 = dinv[s0], w1 = dinv[s1], w2 = dinv[s2], w3 = dinv[s3];
      acc += w0*bf2f(hin[(size_t)s0*64 + lane]);
      acc += w1*bf2f(hin[(size_t)s1*64 + lane]);
      acc += w2*bf2f(hin[(size_t)s2*64 + lane]);
      acc += w3*bf2f(hin[(size_t)s3*64 + lane]);
    }
    for (; j < j1; ++j){
      int s = ebuf[j];
      acc += dinv[s]*bf2f(hin[(size_t)s*64 + lane]);
    }
    float z = fmaxf(di*acc + b, 0.f);
    if (FUSE) fsum += z;
    else ((unsigned short*)outp)[(size_t)i*64 + lane] = (unsigned short)f2bf(z);
  }
  if (FUSE){
    __shared__ float sm[4][64];
    sm[wid][lane] = fsum;
    __syncthreads();
    if (wid == 0)
      ((float*)outp)[(size_t)blockIdx.x*64 + lane] = sm[0][lane] + sm[1][lane] + sm[2][lane] + sm[3][lane];
  }
}

__global__ __launch_bounds__(256) void k_final(const float* __restrict__ part, float* __restrict__ out,
                                               int NB, float invN){
  int f = blockIdx.x;
  float s = 0.f;
  for (int b = threadIdx.x; b < NB; b += 256) s += part[(size_t)b*64 + f];
  __shared__ float sm[256];
  sm[threadIdx.x] = s; __syncthreads();
  for (int d = 128; d > 0; d >>= 1){
    if (threadIdx.x < d) sm[threadIdx.x] += sm[threadIdx.x + d];
    __syncthreads();
  }
  if (threadIdx.x == 0) out[f] = sm[0]*invN;
}

extern "C" void kernel_launch(void* const* d_in, const int* in_sizes, int n_in,
                              void* d_out, int out_size, void* d_ws, size_t ws_size,
                              hipStream_t stream){
  const float* x  = (const float*)d_in[0];
  const int*   ei = (const int*)d_in[1];
  const float* W1 = (const float*)d_in[2];
  const float* b1 = (const float*)d_in[3];
  const float* W2 = (const float*)d_in[4];
  const float* b2 = (const float*)d_in[5];
  float* out = (float*)d_out;

  const int IN = 2048;
  int N = in_sizes[0] / IN;      // 50000
  int E = in_sizes[1] / 2;       // 1.6M

  char* w = (char*)d_ws;
  auto alloc = [&](size_t bytes){ char* p = w; w += (bytes + 255) & ~255ULL; return (void*)p; };
  int*   cnt16   = (int*)  alloc((size_t)16*N*4);
  int*   off     = (int*)  alloc((size_t)(N+1)*4);
  int*   sbase   = (int*)  alloc((size_t)16*N*4);
  float* dinv    = (float*)alloc((size_t)N*4);
  int*   partial = (int*)  alloc(256*4);
  int*   rank    = (int*)  alloc((size_t)E*4);
  int*   ebuf    = (int*)  alloc((size_t)E*4);
  short* Wb1     = (short*)alloc((size_t)64*2048*2);
  short* Wb2     = (short*)alloc((size_t)2*2048*2);
  unsigned short* h1 = (unsigned short*)alloc((size_t)N*64*2);
  unsigned short* z1 = (unsigned short*)alloc((size_t)N*64*2);
  const int NB2 = 2048;
  float* part    = (float*)alloc((size_t)NB2*64*4);

  int EB = (E + 255)/256;            // 6250
  int GB = (N + 63)/64;              // 782 ; 782*2048 >= E (hist slices cover all edges)
  int smblocks = ((N + 15)/16 + 3)/4;

  hipMemsetAsync(cnt16, 0, (size_t)16*N*4, stream);
  k_wconv2 <<<(64*2048 + 2*2048 + 255)/256, 256, 0, stream>>>(W1, Wb1, W2, Wb2);
  k_gemm1_hist<<<GB, 256, 0, stream>>>(x, Wb1, h1, N, ei, cnt16, rank, E, N);
  k_part   <<<256, 256, 0, stream>>>(cnt16, partial, N);
  k_scan2  <<<256, 256, 0, stream>>>(cnt16, partial, off, sbase, dinv, N);
  k_scatter<<<EB, 256, 0, stream>>>(ei, sbase, rank, ebuf, E, N);
  k_agg<false><<<NB2, 256, 0, stream>>>(h1, off, ebuf, dinv, b1, (void*)z1, N);
  k_gemm_sm<2><<<smblocks, 256, 0, stream>>>(z1, Wb2, h1, N, 64);
  k_agg<true> <<<NB2, 256, 0, stream>>>(h1, off, ebuf, dinv, b2, (void*)part, N);
  k_final  <<<64, 256, 0, stream>>>(part, out, NB2, 1.0f/(float)N);
}

// Round 18
// 323.618 us; speedup vs baseline: 1.0570x; 1.0570x over previous
//
#include <hip/hip_runtime.h>
#include <hip/hip_bf16.h>

typedef __attribute__((ext_vector_type(8))) short short8_t;
typedef __attribute__((ext_vector_type(4))) float f32x4;

__device__ __forceinline__ short f2bf(float x){
  union { float f; unsigned u; } v; v.f = x;
  unsigned r = v.u + 0x7fffu + ((v.u >> 16) & 1u);
  return (short)(r >> 16);
}
__device__ __forceinline__ float bf2f(unsigned short u){
  union { unsigned u; float f; } v; v.u = ((unsigned)u) << 16; return v.f;
}
// non-volatile pure value op: compiler schedules freely
__device__ __forceinline__ unsigned cvtpk(float lo, float hi){
  unsigned r; asm("v_cvt_pk_bf16_f32 %0, %1, %2" : "=v"(r) : "v"(lo), "v"(hi)); return r;
}
// async global->LDS, 16B/lane, LDS dest = uniform base + lane*16 (linear)
__device__ __forceinline__ void gll16(const float* g, void* l){
  __builtin_amdgcn_global_load_lds((const __attribute__((address_space(1))) char*)g,
                                   (__attribute__((address_space(3))) char*)l, 16, 0, 0);
}

// Both W -> bf16 fragment layouts in one launch.
__global__ __launch_bounds__(256) void k_wconv2(const float* __restrict__ W1, short* __restrict__ Wb1,
                                                const float* __restrict__ W2, short* __restrict__ Wb2){
  int tid = blockIdx.x*256 + threadIdx.x;
  const float* W; short* Wb; int t;
  if (tid < 64*2048){ W = W1; Wb = Wb1; t = tid; }
  else if (tid < 64*2048 + 2*2048){ W = W2; Wb = Wb2; t = tid - 64*2048; }
  else return;
  int e  = t & 7;
  int l  = (t >> 3) & 63;
  int nt = (t >> 9) & 3;
  int kt = t >> 11;
  int k  = kt*32 + (l >> 4)*8 + e;
  int col = nt*16 + (l & 15);
  Wb[t] = f2bf(W[(size_t)k*64 + col]);
}

// GEMM1 — R12-exact staging (best measured: total 319.6us): per-row gll16 x16 into
// 1040B-pitch LDS, vmcnt(0) drain per 256-col ko-step, 66.5KB -> 2 blocks/CU.
// cvt_pk on consume (zero staging VALU). Unscaled bf16 out + sharded hist tail.
__global__ __launch_bounds__(256) void k_gemm1_hist(const float* __restrict__ A, const short* __restrict__ Wb,
                                                    unsigned short* __restrict__ h1, int M,
                                                    const int* __restrict__ ei, int* __restrict__ cnt16,
                                                    int* __restrict__ rank, int E, int N){
  __shared__ char lds[4*16*1040];   // 66560 B -> 2 blocks/CU
  int b = blockIdx.x, tid = threadIdx.x;
  int wid = tid >> 6, lane = tid & 63;
  int row0 = b*64 + wid*16;
  int rfrag = lane & 15, grp = lane >> 4;
  char* wls = lds + wid*16*1040;    // wave-private region: no barriers
  const short8_t* wb = (const short8_t*)Wb + lane;
  f32x4 acc0 = {0.f,0.f,0.f,0.f}, acc1 = acc0, acc2 = acc0, acc3 = acc0;

  int rowc[16];
  #pragma unroll
  for (int r = 0; r < 16; ++r){
    int rc = row0 + r; rowc[r] = (rc < M) ? rc : (M - 1);
  }

  for (int ko = 0; ko < 8; ++ko){
    #pragma unroll
    for (int r = 0; r < 16; ++r)
      gll16(A + (size_t)rowc[r]*2048 + ko*256 + lane*4, wls + r*1040);
    asm volatile("s_waitcnt vmcnt(0)" ::: "memory");
    __builtin_amdgcn_sched_barrier(0);
    #pragma unroll
    for (int kt = 0; kt < 8; ++kt){
      const float* fp = (const float*)(wls + rfrag*1040 + (kt*32 + grp*8)*4);
      float4 a0 = *(const float4*)fp;
      float4 a1 = *(const float4*)(fp + 4);
      union { unsigned u[4]; short8_t s; } af;
      af.u[0] = cvtpk(a0.x, a0.y);
      af.u[1] = cvtpk(a0.z, a0.w);
      af.u[2] = cvtpk(a1.x, a1.y);
      af.u[3] = cvtpk(a1.z, a1.w);
      int ktg = ko*8 + kt;
      short8_t b0 = wb[(ktg*4+0)*64];
      short8_t b1 = wb[(ktg*4+1)*64];
      short8_t b2 = wb[(ktg*4+2)*64];
      short8_t b3 = wb[(ktg*4+3)*64];
      acc0 = __builtin_amdgcn_mfma_f32_16x16x32_bf16(af.s, b0, acc0, 0,0,0);
      acc1 = __builtin_amdgcn_mfma_f32_16x16x32_bf16(af.s, b1, acc1, 0,0,0);
      acc2 = __builtin_amdgcn_mfma_f32_16x16x32_bf16(af.s, b2, acc2, 0,0,0);
      acc3 = __builtin_amdgcn_mfma_f32_16x16x32_bf16(af.s, b3, acc3, 0,0,0);
    }
  }

  // C/D: col = lane&15, row = (lane>>4)*4 + reg ; unscaled bf16, guarded
  int orow = row0 + grp*4;
  unsigned short* op = h1 + (size_t)orow*64 + rfrag;
  #pragma unroll
  for (int reg = 0; reg < 4; ++reg){
    if (orow + reg < M){
      op[reg*64 +  0] = (unsigned short)f2bf(acc0[reg]);
      op[reg*64 + 16] = (unsigned short)f2bf(acc1[reg]);
      op[reg*64 + 32] = (unsigned short)f2bf(acc2[reg]);
      op[reg*64 + 48] = (unsigned short)f2bf(acc3[reg]);
    }
  }

  // ---- tail: sharded histogram slice (2048 edges/block, shard = b&15) ----
  int lo = b << 11, hi = lo + 2048; if (hi > E) hi = E;
  int* cs = cnt16 + (size_t)(b & 15)*N;
  for (int i = lo + tid; i < hi; i += 256)
    rank[i] = atomicAdd(&cs[ei[E + i]], 1);
}

// ---- parallel scan over sharded counts ----
__global__ __launch_bounds__(256) void k_part(const int* __restrict__ cnt16, int* __restrict__ partial, int N){
  int b = blockIdx.x, t = threadIdx.x;
  int chunk = (N + 255) >> 8;
  int lo = b*chunk, hi = lo + chunk; if (hi > N) hi = N;
  int s = 0;
  for (int i = lo + t; i < hi; i += 256){
    #pragma unroll
    for (int sh = 0; sh < 16; ++sh) s += cnt16[(size_t)sh*N + i];
  }
  __shared__ int sm[256];
  sm[t] = s; __syncthreads();
  for (int d = 128; d; d >>= 1){ if (t < d) sm[t] += sm[t+d]; __syncthreads(); }
  if (t == 0) partial[b] = sm[0];
}

__global__ __launch_bounds__(256) void k_scan2(const int* __restrict__ cnt16, const int* __restrict__ partial,
                                               int* __restrict__ off, int* __restrict__ sbase,
                                               float* __restrict__ dinv, int N){
  int b = blockIdx.x, t = threadIdx.x;
  __shared__ int ps[256];
  ps[t] = partial[t]; __syncthreads();
  for (int d = 1; d < 256; d <<= 1){
    int v = (t >= d) ? ps[t-d] : 0; __syncthreads(); ps[t] += v; __syncthreads();
  }
  int base  = b ? ps[b-1] : 0;
  int total = ps[255];
  int chunk = (N + 255) >> 8;
  int lo = b*chunk, hi = lo + chunk; if (hi > N) hi = N;
  __shared__ int vs[256];
  int run = base;
  for (int j0 = lo; j0 < hi; j0 += 256){
    int i = j0 + t;
    int cs[16]; int c = 0;
    if (i < hi){
      #pragma unroll
      for (int sh = 0; sh < 16; ++sh){ cs[sh] = cnt16[(size_t)sh*N + i]; c += cs[sh]; }
    }
    vs[t] = (i < hi) ? c : 0; __syncthreads();
    for (int d = 1; d < 256; d <<= 1){
      int v = (t >= d) ? vs[t-d] : 0; __syncthreads(); vs[t] += v; __syncthreads();
    }
    if (i < hi){
      int excl = run + vs[t] - c;
      off[i] = excl;
      dinv[i] = rsqrtf((float)(c + 1));
      int runs = excl;
      #pragma unroll
      for (int sh = 0; sh < 16; ++sh){ sbase[(size_t)sh*N + i] = runs; runs += cs[sh]; }
    }
    run += vs[255];
    __syncthreads();
  }
  if (b == 255 && t == 0) off[N] = total;
}

// Atomic-free scatter: shard = (i>>11)&15 (matches 2048-edge hist slices).
__global__ __launch_bounds__(256) void k_scatter(const int* __restrict__ ei, const int* __restrict__ sbase,
                                                 const int* __restrict__ rank, int* __restrict__ ebuf,
                                                 int E, int N){
  int i = blockIdx.x*256 + threadIdx.x;
  if (i < E){
    int s = ei[i], d = ei[E + i];
    int sh = (i >> 11) & 15;
    ebuf[sbase[(size_t)sh*N + d] + rank[i]] = s;
  }
}

// GEMM2 (K=64): bf16 A, unscaled bf16 out.
template<int KTILES>
__global__ __launch_bounds__(256) void k_gemm_sm(const unsigned short* __restrict__ Ah,
                                                 const short* __restrict__ Wb,
                                                 unsigned short* __restrict__ out, int M, int lda){
  int wid = threadIdx.x >> 6, lane = threadIdx.x & 63;
  int row0 = (blockIdx.x*4 + wid)*16;
  if (row0 >= M) return;
  int r = lane & 15, g = lane >> 4;
  const short8_t* wb = (const short8_t*)Wb + lane;
  f32x4 acc0 = {0.f,0.f,0.f,0.f}, acc1 = acc0, acc2 = acc0, acc3 = acc0;
  #pragma unroll
  for (int kt = 0; kt < KTILES; ++kt){
    short8_t af = *(const short8_t*)(Ah + (size_t)(row0 + r)*lda + kt*32 + g*8);
    short8_t b0 = wb[(kt*4+0)*64];
    short8_t b1 = wb[(kt*4+1)*64];
    short8_t b2 = wb[(kt*4+2)*64];
    short8_t b3 = wb[(kt*4+3)*64];
    acc0 = __builtin_amdgcn_mfma_f32_16x16x32_bf16(af, b0, acc0, 0,0,0);
    acc1 = __builtin_amdgcn_mfma_f32_16x16x32_bf16(af, b1, acc1, 0,0,0);
    acc2 = __builtin_amdgcn_mfma_f32_16x16x32_bf16(af, b2, acc2, 0,0,0);
    acc3 = __builtin_amdgcn_mfma_f32_16x16x32_bf16(af, b3, acc3, 0,0,0);
  }
  int orow = row0 + g*4;
  unsigned short* op = out + (size_t)orow*64 + r;
  #pragma unroll
  for (int reg = 0; reg < 4; ++reg){
    if (orow + reg < M){
      op[reg*64 +  0] = (unsigned short)f2bf(acc0[reg]);
      op[reg*64 + 16] = (unsigned short)f2bf(acc1[reg]);
      op[reg*64 + 32] = (unsigned short)f2bf(acc2[reg]);
      op[reg*64 + 48] = (unsigned short)f2bf(acc3[reg]);
    }
  }
}

// Gather-aggregate on unscaled h, 8-deep gather pipeline (best measured).
template<bool FUSE>
__global__ __launch_bounds__(256) void k_agg(const unsigned short* __restrict__ hin, const int* __restrict__ off,
                                             const int* __restrict__ ebuf, const float* __restrict__ dinv,
                                             const float* __restrict__ bias, void* __restrict__ outp, int N){
  int lane = threadIdx.x & 63, wid = threadIdx.x >> 6;
  float b = bias[lane];
  float fsum = 0.f;
  int stride = gridDim.x*4;
  for (int i = blockIdx.x*4 + wid; i < N; i += stride){
    float di = dinv[i];
    float acc = di*bf2f(hin[(size_t)i*64 + lane]);
    int j  = off[i];
    int j1 = off[i+1];
    for (; j + 8 <= j1; j += 8){
      int s0 = ebuf[j],   s1 = ebuf[j+1], s2 = ebuf[j+2], s3 = ebuf[j+3];
      int s4 = ebuf[j+4], s5 = ebuf[j+5], s6 = ebuf[j+6], s7 = ebuf[j+7];
      float w0 = dinv[s0], w1 = dinv[s1], w2 = dinv[s2], w3 = dinv[s3];
      float w4 = dinv[s4], w5 = dinv[s5], w6 = dinv[s6], w7 = dinv[s7];
      float h0 = bf2f(hin[(size_t)s0*64 + lane]);
      float h1v = bf2f(hin[(size_t)s1*64 + lane]);
      float h2 = bf2f(hin[(size_t)s2*64 + lane]);
      float h3 = bf2f(hin[(size_t)s3*64 + lane]);
      float h4 = bf2f(hin[(size_t)s4*64 + lane]);
      float h5 = bf2f(hin[(size_t)s5*64 + lane]);
      float h6 = bf2f(hin[(size_t)s6*64 + lane]);
      float h7 = bf2f(hin[(size_t)s7*64 + lane]);
      acc += w0*h0 + w1*h1v + w2*h2 + w3*h3 + w4*h4 + w5*h5 + w6*h6 + w7*h7;
    }
    for (; j < j1; ++j){
      int s = ebuf[j];
      acc += dinv[s]*bf2f(hin[(size_t)s*64 + lane]);
    }
    float z = fmaxf(di*acc + b, 0.f);
    if (FUSE) fsum += z;
    else ((unsigned short*)outp)[(size_t)i*64 + lane] = (unsigned short)f2bf(z);
  }
  if (FUSE){
    __shared__ float sm[4][64];
    sm[wid][lane] = fsum;
    __syncthreads();
    if (wid == 0)
      ((float*)outp)[(size_t)blockIdx.x*64 + lane] = sm[0][lane] + sm[1][lane] + sm[2][lane] + sm[3][lane];
  }
}

__global__ __launch_bounds__(256) void k_final(const float* __restrict__ part, float* __restrict__ out,
                                               int NB, float invN){
  int f = blockIdx.x;
  float s = 0.f;
  for (int b = threadIdx.x; b < NB; b += 256) s += part[(size_t)b*64 + f];
  __shared__ float sm[256];
  sm[threadIdx.x] = s; __syncthreads();
  for (int d = 128; d > 0; d >>= 1){
    if (threadIdx.x < d) sm[threadIdx.x] += sm[threadIdx.x + d];
    __syncthreads();
  }
  if (threadIdx.x == 0) out[f] = sm[0]*invN;
}

extern "C" void kernel_launch(void* const* d_in, const int* in_sizes, int n_in,
                              void* d_out, int out_size, void* d_ws, size_t ws_size,
                              hipStream_t stream){
  const float* x  = (const float*)d_in[0];
  const int*   ei = (const int*)d_in[1];
  const float* W1 = (const float*)d_in[2];
  const float* b1 = (const float*)d_in[3];
  const float* W2 = (const float*)d_in[4];
  const float* b2 = (const float*)d_in[5];
  float* out = (float*)d_out;

  const int IN = 2048;
  int N = in_sizes[0] / IN;      // 50000
  int E = in_sizes[1] / 2;       // 1.6M

  char* w = (char*)d_ws;
  auto alloc = [&](size_t bytes){ char* p = w; w += (bytes + 255) & ~255ULL; return (void*)p; };
  int*   cnt16   = (int*)  alloc((size_t)16*N*4);
  int*   off     = (int*)  alloc((size_t)(N+1)*4);
  int*   sbase   = (int*)  alloc((size_t)16*N*4);
  float* dinv    = (float*)alloc((size_t)N*4);
  int*   partial = (int*)  alloc(256*4);
  int*   rank    = (int*)  alloc((size_t)E*4);
  int*   ebuf    = (int*)  alloc((size_t)E*4);
  short* Wb1     = (short*)alloc((size_t)64*2048*2);
  short* Wb2     = (short*)alloc((size_t)2*2048*2);
  unsigned short* h1 = (unsigned short*)alloc((size_t)N*64*2);
  unsigned short* z1 = (unsigned short*)alloc((size_t)N*64*2);
  const int NB2 = 2048;
  float* part    = (float*)alloc((size_t)NB2*64*4);

  int EB = (E + 255)/256;            // 6250
  int GB = (N + 63)/64;              // 782 ; 782*2048 >= E (hist slices cover all edges)
  int smblocks = ((N + 15)/16 + 3)/4;

  hipMemsetAsync(cnt16, 0, (size_t)16*N*4, stream);
  k_wconv2 <<<(64*2048 + 2*2048 + 255)/256, 256, 0, stream>>>(W1, Wb1, W2, Wb2);
  k_gemm1_hist<<<GB, 256, 0, stream>>>(x, Wb1, h1, N, ei, cnt16, rank, E, N);
  k_part   <<<256, 256, 0, stream>>>(cnt16, partial, N);
  k_scan2  <<<256, 256, 0, stream>>>(cnt16, partial, off, sbase, dinv, N);
  k_scatter<<<EB, 256, 0, stream>>>(ei, sbase, rank, ebuf, E, N);
  k_agg<false><<<NB2, 256, 0, stream>>>(h1, off, ebuf, dinv, b1, (void*)z1, N);
  k_gemm_sm<2><<<smblocks, 256, 0, stream>>>(z1, Wb2, h1, N, 64);
  k_agg<true> <<<NB2, 256, 0, stream>>>(h1, off, ebuf, dinv, b2, (void*)part, N);
  k_final  <<<64, 256, 0, stream>>>(part, out, NB2, 1.0f/(float)N);
}